// Round 1
// baseline (184.004 us; speedup 1.0000x reference)
//
#include <hip/hip_runtime.h>

#define DEV __device__ __forceinline__

typedef __attribute__((ext_vector_type(8))) short bf16x8;
typedef __attribute__((ext_vector_type(4))) float f32x4;

// ---------- helpers ----------
DEV ushort f2bf(float f) {
  union { float f; unsigned u; } x; x.f = f;
  unsigned r = (x.u + 0x7FFFu + ((x.u >> 16) & 1u)) >> 16;
  return (ushort)r;
}

DEV void gload16(const void* g, void* l) {
  __builtin_amdgcn_global_load_lds(
      (const __attribute__((address_space(1))) void*)g,
      (__attribute__((address_space(3))) void*)l, 16, 0, 0);
}

DEV f32x4 mfma16(bf16x8 a, bf16x8 b, f32x4 c) {
  return __builtin_amdgcn_mfma_f32_16x16x32_bf16(a, b, c, 0, 0, 0);
}

// ---------- sizes ----------
#define BB 2
#define SS 2048
#define HH 16
#define DD 64
#define DM 1024
#define MROWS (BB * SS)       // 4096
#define NQKV  (3 * DM)        // 3072

// ---------- convert & pack f32 -> bf16 ----------
__global__ void convert_kernel(const float* __restrict__ hs,
                               const float* __restrict__ Wq, const float* __restrict__ bq,
                               const float* __restrict__ Wk, const float* __restrict__ bk,
                               const float* __restrict__ Wv, const float* __restrict__ bv,
                               const float* __restrict__ Wy,
                               ushort* __restrict__ Xb, ushort* __restrict__ Wqkv,
                               ushort* __restrict__ Wyb, float* __restrict__ bqkv) {
  const int HS_V = (MROWS * DM) / 4;     // 1048576
  const int WQ_V = (NQKV * DM) / 4;      // 786432
  const int WY_V = (DM * DM) / 4;        // 262144
  int idx = blockIdx.x * 256 + threadIdx.x;
  if (idx < HS_V) {
    float4 v = ((const float4*)hs)[idx];
    ushort4 o; o.x = f2bf(v.x); o.y = f2bf(v.y); o.z = f2bf(v.z); o.w = f2bf(v.w);
    ((ushort4*)Xb)[idx] = o;
  } else if (idx < HS_V + WQ_V) {
    int e = (idx - HS_V) * 4;
    int n = e >> 10, k = e & 1023;
    const float* W = (n < 1024) ? Wq : (n < 2048) ? Wk : Wv;
    int nn = n & 1023;
    float4 v = *(const float4*)(W + nn * 1024 + k);
    ushort4 o; o.x = f2bf(v.x); o.y = f2bf(v.y); o.z = f2bf(v.z); o.w = f2bf(v.w);
    ((ushort4*)Wqkv)[idx - HS_V] = o;
  } else if (idx < HS_V + WQ_V + WY_V) {
    int e = idx - HS_V - WQ_V;
    float4 v = ((const float4*)Wy)[e];
    ushort4 o; o.x = f2bf(v.x); o.y = f2bf(v.y); o.z = f2bf(v.z); o.w = f2bf(v.w);
    ((ushort4*)Wyb)[e] = o;
  }
  if (idx < NQKV)
    bqkv[idx] = (idx < 1024) ? bq[idx] : (idx < 2048) ? bk[idx - 1024] : bv[idx - 2048];
}

// ---------- GEMM: C[m,n] = sum_k A[m,k]*Bw[n,k] + bias[n] ----------
// A bf16 [M,K], Bw bf16 [N,K], 128x128 tile, BK=32, 4 waves (2x2), 64x64 per wave.
template <bool OUT_F32>
__global__ void gemm_bt(const ushort* __restrict__ A, const ushort* __restrict__ Bw,
                        const float* __restrict__ bias, void* __restrict__ Cout,
                        int M, int N, int K) {
  __shared__ ushort Al[128 * 32];
  __shared__ ushort Bl[128 * 32];
  const int tid = threadIdx.x;
  const int lane = tid & 63;
  const int wave = tid >> 6;
  const int lg = lane >> 4, l15 = lane & 15;
  const int m0 = blockIdx.x * 128, n0 = blockIdx.y * 128;
  const int wm = (wave >> 1) * 64, wn = (wave & 1) * 64;

  f32x4 acc[4][4] = {};

  for (int k0 = 0; k0 < K; k0 += 32) {
    // stage A and B tiles (128x32 bf16 each), XOR-swizzled via global source
#pragma unroll
    for (int is = 0; is < 2; ++is) {
      int f = tid * 8 + is * 2048;          // bf16 elems
      int row = f >> 5;                     // 0..127
      int c = (f >> 3) & 3;                 // 16B chunk in row
      int cs = c ^ ((row >> 1) & 3);
      gload16(A + (size_t)(m0 + row) * K + k0 + cs * 8,
              (char*)Al + tid * 16 + is * 4096);
      gload16(Bw + (size_t)(n0 + row) * K + k0 + cs * 8,
              (char*)Bl + tid * 16 + is * 4096);
    }
    __syncthreads();

    bf16x8 af[4], bfr[4];
#pragma unroll
    for (int i = 0; i < 4; ++i) {
      int rA = wm + i * 16 + l15;
      int cA = lg ^ ((rA >> 1) & 3);
      af[i] = *(const bf16x8*)((const char*)Al + rA * 64 + cA * 16);
      int rB = wn + i * 16 + l15;
      int cB = lg ^ ((rB >> 1) & 3);
      bfr[i] = *(const bf16x8*)((const char*)Bl + rB * 64 + cB * 16);
    }
#pragma unroll
    for (int i = 0; i < 4; ++i)
#pragma unroll
      for (int j = 0; j < 4; ++j)
        acc[i][j] = mfma16(af[i], bfr[j], acc[i][j]);
    __syncthreads();
  }

#pragma unroll
  for (int i = 0; i < 4; ++i) {
#pragma unroll
    for (int j = 0; j < 4; ++j) {
      int n = n0 + wn + j * 16 + l15;
      float bv = bias[n];
#pragma unroll
      for (int r = 0; r < 4; ++r) {
        int m = m0 + wm + i * 16 + lg * 4 + r;
        float v = acc[i][j][r] + bv;
        if (OUT_F32)
          ((float*)Cout)[(size_t)m * N + n] = v;
        else
          ((ushort*)Cout)[(size_t)m * N + n] = f2bf(v);
      }
    }
  }
}

// ---------- transpose V section of QKV into Vt [b,h,d,s] ----------
__global__ void transpose_v(const ushort* __restrict__ QKV, ushort* __restrict__ Vt) {
  __shared__ ushort tl[64][72];
  const int tid = threadIdx.x;
  const int bh = blockIdx.y, b = bh >> 4, h = bh & 15;
  const int s0 = blockIdx.x * 64;
  {
    int s = tid >> 2, d0 = (tid & 3) * 16;
    const ushort* src = QKV + (size_t)(b * SS + s0 + s) * NQKV + 2 * DM + h * DD + d0;
    bf16x8 v0 = *(const bf16x8*)(src);
    bf16x8 v1 = *(const bf16x8*)(src + 8);
#pragma unroll
    for (int i = 0; i < 8; ++i) tl[d0 + i][s] = (ushort)v0[i];
#pragma unroll
    for (int i = 0; i < 8; ++i) tl[d0 + 8 + i][s] = (ushort)v1[i];
  }
  __syncthreads();
  {
    int d = tid >> 2, s1 = (tid & 3) * 16;
    ushort* dst = Vt + (size_t)(bh * DD + d) * SS + s0 + s1;
    *(bf16x8*)(dst) = *(const bf16x8*)&tl[d][s1];
    *(bf16x8*)(dst + 8) = *(const bf16x8*)&tl[d][s1 + 8];
  }
}

// ---------- flash attention ----------
// grid (S/64, B*H); 256 threads = 4 waves, each wave 16 q-rows. KVBLK=64.
__global__ void attn_kernel(const ushort* __restrict__ QKV, const ushort* __restrict__ Vt,
                            ushort* __restrict__ O) {
  __shared__ ushort Klds[64 * 64];   // [t][d], chunk-swizzled ^ (t&7)
  __shared__ ushort Vlds[64 * 64];   // [d][t], chunk-swizzled ^ (d&7)
  __shared__ ushort Plds[4][16 * 64];// per-wave [q][t], swizzled ^ (q&7)

  const int tid = threadIdx.x;
  const int wave = tid >> 6, lane = tid & 63;
  const int lg = lane >> 4, l15 = lane & 15;
  const int bh = blockIdx.y, b = bh >> 4, h = bh & 15;
  const int q0 = blockIdx.x * 64;

  // Q A-frags, held in registers for the whole kernel
  const ushort* Qg = QKV + (size_t)(b * SS + q0 + wave * 16 + l15) * NQKV + h * DD;
  bf16x8 qf0 = *(const bf16x8*)(Qg + lg * 8);
  bf16x8 qf1 = *(const bf16x8*)(Qg + lg * 8 + 32);

  float m_run[4] = {-1e30f, -1e30f, -1e30f, -1e30f};
  float l_run[4] = {0.f, 0.f, 0.f, 0.f};
  f32x4 o_acc[4] = {};

  const int nkv = blockIdx.x + 1;
  for (int kvb = 0; kvb < nkv; ++kvb) {
    const int kv0 = kvb * 64;
    // stage K (rows t, 64 d) and Vt (rows d, 64 t)
#pragma unroll
    for (int is = 0; is < 2; ++is) {
      int f = tid * 8 + is * 2048;
      int r = f >> 6;              // row 0..63
      int c = (f >> 3) & 7;        // chunk 0..7
      int cs = c ^ (r & 7);
      gload16(QKV + (size_t)(b * SS + kv0 + r) * NQKV + DM + h * DD + cs * 8,
              (char*)Klds + tid * 16 + is * 4096);
      gload16(Vt + (size_t)(bh * DD + r) * SS + kv0 + cs * 8,
              (char*)Vlds + tid * 16 + is * 4096);
    }
    __syncthreads();

    // QK^T: sc[tt] covers t = kv0 + tt*16 + l15, q = q0 + wave*16 + lg*4 + r
    f32x4 sc[4];
#pragma unroll
    for (int tt = 0; tt < 4; ++tt) {
      int t = tt * 16 + l15;
      int c0 = lg ^ (t & 7);
      int c1 = (lg + 4) ^ (t & 7);
      bf16x8 kf0 = *(const bf16x8*)((const char*)Klds + t * 128 + c0 * 16);
      bf16x8 kf1 = *(const bf16x8*)((const char*)Klds + t * 128 + c1 * 16);
      f32x4 a = {};
      a = mfma16(qf0, kf0, a);
      a = mfma16(qf1, kf1, a);
      sc[tt] = a;
    }
    const bool diag = (kvb == nkv - 1);
#pragma unroll
    for (int tt = 0; tt < 4; ++tt) {
#pragma unroll
      for (int r = 0; r < 4; ++r) {
        float v = sc[tt][r] * 0.125f;  // 1/sqrt(64)
        if (diag) {
          int T = kv0 + tt * 16 + l15;
          int Qi = q0 + wave * 16 + lg * 4 + r;
          if (T > Qi) v = -1e30f;
        }
        sc[tt][r] = v;
      }
    }
    // row max over 64 t
    float pm[4];
#pragma unroll
    for (int r = 0; r < 4; ++r)
      pm[r] = fmaxf(fmaxf(sc[0][r], sc[1][r]), fmaxf(sc[2][r], sc[3][r]));
#pragma unroll
    for (int msk = 1; msk <= 8; msk <<= 1)
#pragma unroll
      for (int r = 0; r < 4; ++r)
        pm[r] = fmaxf(pm[r], __shfl_xor(pm[r], msk, 64));

    float mnew[4], alpha[4], psum[4];
#pragma unroll
    for (int r = 0; r < 4; ++r) {
      mnew[r] = fmaxf(m_run[r], pm[r]);
      alpha[r] = __expf(m_run[r] - mnew[r]);
      psum[r] = 0.f;
    }
#pragma unroll
    for (int tt = 0; tt < 4; ++tt)
#pragma unroll
      for (int r = 0; r < 4; ++r) {
        float p = __expf(sc[tt][r] - mnew[r]);
        sc[tt][r] = p;
        psum[r] += p;
      }
#pragma unroll
    for (int msk = 1; msk <= 8; msk <<= 1)
#pragma unroll
      for (int r = 0; r < 4; ++r)
        psum[r] += __shfl_xor(psum[r], msk, 64);
#pragma unroll
    for (int r = 0; r < 4; ++r) {
      l_run[r] = l_run[r] * alpha[r] + psum[r];
      m_run[r] = mnew[r];
    }
#pragma unroll
    for (int dt = 0; dt < 4; ++dt)
#pragma unroll
      for (int r = 0; r < 4; ++r) o_acc[dt][r] *= alpha[r];

    // write P to per-wave LDS (swizzled), then read as A-frags
    ushort* Pw = Plds[wave];
#pragma unroll
    for (int tt = 0; tt < 4; ++tt)
#pragma unroll
      for (int r = 0; r < 4; ++r) {
        int q = lg * 4 + r;
        int t = tt * 16 + l15;
        int cs = (t >> 3) ^ (q & 7);
        Pw[q * 64 + cs * 8 + (t & 7)] = f2bf(sc[tt][r]);
      }

    // PV
#pragma unroll
    for (int dt = 0; dt < 4; ++dt) {
      int d = dt * 16 + l15;
#pragma unroll
      for (int kk = 0; kk < 2; ++kk) {
        int cp = (lg + kk * 4) ^ (l15 & 7);
        bf16x8 pf = *(const bf16x8*)((const char*)Pw + l15 * 128 + cp * 16);
        int cv = (lg + kk * 4) ^ (d & 7);
        bf16x8 vf = *(const bf16x8*)((const char*)Vlds + d * 128 + cv * 16);
        o_acc[dt] = mfma16(pf, vf, o_acc[dt]);
      }
    }
    __syncthreads();
  }

  // epilogue: O[b, q, h*64+d] = o_acc / l_run
  float inv[4];
#pragma unroll
  for (int r = 0; r < 4; ++r) inv[r] = 1.0f / l_run[r];
#pragma unroll
  for (int dt = 0; dt < 4; ++dt)
#pragma unroll
    for (int r = 0; r < 4; ++r) {
      int q = q0 + wave * 16 + lg * 4 + r;
      O[(size_t)(b * SS + q) * DM + h * DD + dt * 16 + l15] = f2bf(o_acc[dt][r] * inv[r]);
    }
}

// ---------- launch ----------
extern "C" void kernel_launch(void* const* d_in, const int* in_sizes, int n_in,
                              void* d_out, int out_size, void* d_ws, size_t ws_size,
                              hipStream_t stream) {
  const float* hs = (const float*)d_in[0];
  const float* Wq = (const float*)d_in[1];
  const float* bq = (const float*)d_in[2];
  const float* Wk = (const float*)d_in[3];
  const float* bk = (const float*)d_in[4];
  const float* Wv = (const float*)d_in[5];
  const float* bv = (const float*)d_in[6];
  const float* Wy = (const float*)d_in[7];
  const float* by = (const float*)d_in[8];
  float* out = (float*)d_out;

  char* ws = (char*)d_ws;
  ushort* Xb   = (ushort*)(ws);                          // 8 MiB  [4096][1024] bf16
  ushort* Wqkv = (ushort*)(ws + (8ull  << 20));          // 6 MiB  [3072][1024] bf16
  ushort* Wyb  = (ushort*)(ws + (14ull << 20));          // 2 MiB  [1024][1024] bf16
  float*  bqkv = (float*) (ws + (16ull << 20));          // 12 KiB
  ushort* QKV  = (ushort*)(ws + (17ull << 20));          // 24 MiB [4096][3072] bf16
  ushort* Vt   = (ushort*)(ws + (41ull << 20));          // 8 MiB  [32][64][2048] bf16
  ushort* Ob   = (ushort*)(ws + (49ull << 20));          // 8 MiB  [4096][1024] bf16

  convert_kernel<<<dim3(8192), dim3(256), 0, stream>>>(hs, Wq, bq, Wk, bk, Wv, bv, Wy,
                                                       Xb, Wqkv, Wyb, bqkv);
  gemm_bt<false><<<dim3(32, 24), dim3(256), 0, stream>>>(Xb, Wqkv, bqkv, QKV,
                                                         MROWS, NQKV, DM);
  transpose_v<<<dim3(32, 32), dim3(256), 0, stream>>>(QKV, Vt);
  attn_kernel<<<dim3(32, 32), dim3(256), 0, stream>>>(QKV, Vt, Ob);
  gemm_bt<true><<<dim3(32, 8), dim3(256), 0, stream>>>(Ob, Wyb, by, out,
                                                       MROWS, DM, DM);
}

// Round 2
// 146.934 us; speedup vs baseline: 1.2523x; 1.2523x over previous
//
#include <hip/hip_runtime.h>

#define DEV __device__ __forceinline__

typedef __attribute__((ext_vector_type(8))) short bf16x8;
typedef __attribute__((ext_vector_type(4))) float f32x4;

// ---------- helpers ----------
DEV ushort f2bf(float f) {
  union { float f; unsigned u; } x; x.f = f;
  unsigned r = (x.u + 0x7FFFu + ((x.u >> 16) & 1u)) >> 16;
  return (ushort)r;
}

DEV void gload16(const void* g, void* l) {
  __builtin_amdgcn_global_load_lds(
      (const __attribute__((address_space(1))) void*)g,
      (__attribute__((address_space(3))) void*)l, 16, 0, 0);
}

DEV f32x4 mfma16(bf16x8 a, bf16x8 b, f32x4 c) {
  return __builtin_amdgcn_mfma_f32_16x16x32_bf16(a, b, c, 0, 0, 0);
}

// ---------- sizes ----------
#define BB 2
#define SS 2048
#define HH 16
#define DD 64
#define DM 1024
#define MROWS (BB * SS)       // 4096
#define NQKV  (3 * DM)        // 3072

// ---------- convert & pack f32 -> bf16 ----------
__global__ void convert_kernel(const float* __restrict__ hs,
                               const float* __restrict__ Wq, const float* __restrict__ bq,
                               const float* __restrict__ Wk, const float* __restrict__ bk,
                               const float* __restrict__ Wv, const float* __restrict__ bv,
                               const float* __restrict__ Wy,
                               ushort* __restrict__ Xb, ushort* __restrict__ Wqkv,
                               ushort* __restrict__ Wyb, float* __restrict__ bqkv) {
  const int HS_V = (MROWS * DM) / 4;     // 1048576
  const int WQ_V = (NQKV * DM) / 4;      // 786432
  const int WY_V = (DM * DM) / 4;        // 262144
  int idx = blockIdx.x * 256 + threadIdx.x;
  if (idx < HS_V) {
    float4 v = ((const float4*)hs)[idx];
    ushort4 o; o.x = f2bf(v.x); o.y = f2bf(v.y); o.z = f2bf(v.z); o.w = f2bf(v.w);
    ((ushort4*)Xb)[idx] = o;
  } else if (idx < HS_V + WQ_V) {
    int e = (idx - HS_V) * 4;
    int n = e >> 10, k = e & 1023;
    const float* W = (n < 1024) ? Wq : (n < 2048) ? Wk : Wv;
    int nn = n & 1023;
    float4 v = *(const float4*)(W + nn * 1024 + k);
    ushort4 o; o.x = f2bf(v.x); o.y = f2bf(v.y); o.z = f2bf(v.z); o.w = f2bf(v.w);
    ((ushort4*)Wqkv)[idx - HS_V] = o;
  } else if (idx < HS_V + WQ_V + WY_V) {
    int e = idx - HS_V - WQ_V;
    float4 v = ((const float4*)Wy)[e];
    ushort4 o; o.x = f2bf(v.x); o.y = f2bf(v.y); o.z = f2bf(v.z); o.w = f2bf(v.w);
    ((ushort4*)Wyb)[e] = o;
  }
  if (idx < NQKV)
    bqkv[idx] = (idx < 1024) ? bq[idx] : (idx < 2048) ? bk[idx - 1024] : bv[idx - 2048];
}

// ---------- GEMM: C[m,n] = (sum_k A[m,k]*Bw[n,k] + bias[n]) * (n<scaleN ? 0.125 : 1) ----------
template <bool OUT_F32>
__global__ void gemm_bt(const ushort* __restrict__ A, const ushort* __restrict__ Bw,
                        const float* __restrict__ bias, void* __restrict__ Cout,
                        int M, int N, int K, int scaleN) {
  __shared__ ushort Al[128 * 32];
  __shared__ ushort Bl[128 * 32];
  const int tid = threadIdx.x;
  const int lane = tid & 63;
  const int wave = tid >> 6;
  const int lg = lane >> 4, l15 = lane & 15;
  const int m0 = blockIdx.x * 128, n0 = blockIdx.y * 128;
  const int wm = (wave >> 1) * 64, wn = (wave & 1) * 64;

  f32x4 acc[4][4] = {};

  for (int k0 = 0; k0 < K; k0 += 32) {
#pragma unroll
    for (int is = 0; is < 2; ++is) {
      int f = tid * 8 + is * 2048;          // bf16 elems
      int row = f >> 5;                     // 0..127
      int c = (f >> 3) & 3;                 // 16B chunk in row
      int cs = c ^ ((row >> 1) & 3);
      gload16(A + (size_t)(m0 + row) * K + k0 + cs * 8,
              (char*)Al + tid * 16 + is * 4096);
      gload16(Bw + (size_t)(n0 + row) * K + k0 + cs * 8,
              (char*)Bl + tid * 16 + is * 4096);
    }
    __syncthreads();

    bf16x8 af[4], bfr[4];
#pragma unroll
    for (int i = 0; i < 4; ++i) {
      int rA = wm + i * 16 + l15;
      int cA = lg ^ ((rA >> 1) & 3);
      af[i] = *(const bf16x8*)((const char*)Al + rA * 64 + cA * 16);
      int rB = wn + i * 16 + l15;
      int cB = lg ^ ((rB >> 1) & 3);
      bfr[i] = *(const bf16x8*)((const char*)Bl + rB * 64 + cB * 16);
    }
#pragma unroll
    for (int i = 0; i < 4; ++i)
#pragma unroll
      for (int j = 0; j < 4; ++j)
        acc[i][j] = mfma16(af[i], bfr[j], acc[i][j]);
    __syncthreads();
  }

#pragma unroll
  for (int i = 0; i < 4; ++i) {
#pragma unroll
    for (int j = 0; j < 4; ++j) {
      int n = n0 + wn + j * 16 + l15;
      float bv = bias[n];
      float qs = (n < scaleN) ? 0.125f : 1.0f;
#pragma unroll
      for (int r = 0; r < 4; ++r) {
        int m = m0 + wm + i * 16 + lg * 4 + r;
        float v = (acc[i][j][r] + bv) * qs;
        if (OUT_F32)
          ((float*)Cout)[(size_t)m * N + n] = v;
        else
          ((ushort*)Cout)[(size_t)m * N + n] = f2bf(v);
      }
    }
  }
}

// ---------- transpose V section of QKV into Vt [b,h,d,s] ----------
__global__ void transpose_v(const ushort* __restrict__ QKV, ushort* __restrict__ Vt) {
  __shared__ ushort tl[64][72];
  const int tid = threadIdx.x;
  const int bh = blockIdx.y, b = bh >> 4, h = bh & 15;
  const int s0 = blockIdx.x * 64;
  {
    int s = tid >> 2, d0 = (tid & 3) * 16;
    const ushort* src = QKV + (size_t)(b * SS + s0 + s) * NQKV + 2 * DM + h * DD + d0;
    bf16x8 v0 = *(const bf16x8*)(src);
    bf16x8 v1 = *(const bf16x8*)(src + 8);
#pragma unroll
    for (int i = 0; i < 8; ++i) tl[d0 + i][s] = (ushort)v0[i];
#pragma unroll
    for (int i = 0; i < 8; ++i) tl[d0 + 8 + i][s] = (ushort)v1[i];
  }
  __syncthreads();
  {
    int d = tid >> 2, s1 = (tid & 3) * 16;
    ushort* dst = Vt + (size_t)(bh * DD + d) * SS + s0 + s1;
    *(bf16x8*)(dst) = *(const bf16x8*)&tl[d][s1];
    *(bf16x8*)(dst + 8) = *(const bf16x8*)&tl[d][s1 + 8];
  }
}

// ---------- flash attention, causal-paired, double-buffered ----------
// grid (8, B*H); 512 threads = 8 waves, each wave 16 q-rows. QBLK=128, KVBLK=64.
// Block pairi handles q-tiles {pairi, 15-pairi}: 2*i+2 + 32-2*i = 34 kv-iters, balanced.
__global__ __launch_bounds__(512)
void attn_kernel(const ushort* __restrict__ QKV, const ushort* __restrict__ Vt,
                 ushort* __restrict__ O) {
  __shared__ ushort Klds[2][64 * 64];   // [t][d], chunk-swizzled ^ (t&7)
  __shared__ ushort Vlds[2][64 * 64];   // [d][t], chunk-swizzled ^ (d&7)
  __shared__ ushort Plds[8][16 * 64];   // per-wave [q][t], swizzled

  const int tid = threadIdx.x;
  const int wave = tid >> 6, lane = tid & 63;
  const int lg = lane >> 4, l15 = lane & 15;
  const int bh = blockIdx.y, b = bh >> 4, h = bh & 15;
  const int pairi = blockIdx.x;

  // staging address components (same for every kv block modulo kv0)
  const int sr = tid >> 3;              // row 0..63
  const int scs = (tid & 7) ^ (sr & 7); // swizzled 16B chunk
  const ushort* Kg0 = QKV + (size_t)(b * SS + sr) * NQKV + DM + h * DD + scs * 8;
  const ushort* Vg0 = Vt + (size_t)(bh * DD + sr) * SS + scs * 8;

#pragma unroll 1
  for (int ph = 0; ph < 2; ++ph) {
    const int qt = ph ? (15 - pairi) : pairi;
    const int q0 = qt * 128;
    const int nkv = 2 * qt + 2;
    const int q_min = q0 + wave * 16;

    // Q A-frags (scale 1/8 already folded in by the QKV GEMM epilogue)
    const ushort* Qg = QKV + (size_t)(b * SS + q0 + wave * 16 + l15) * NQKV + h * DD;
    bf16x8 qf0 = *(const bf16x8*)(Qg + lg * 8);
    bf16x8 qf1 = *(const bf16x8*)(Qg + lg * 8 + 32);

    float m_run[4] = {-1e30f, -1e30f, -1e30f, -1e30f};
    float l_run[4] = {0.f, 0.f, 0.f, 0.f};
    f32x4 o_acc[4] = {};

    // prologue: stage kv block 0 into buffer 0
    gload16(Kg0, (char*)Klds[0] + tid * 16);
    gload16(Vg0, (char*)Vlds[0] + tid * 16);

#pragma unroll 1
    for (int kvb = 0; kvb < nkv; ++kvb) {
      const int cur = kvb & 1;
      const int kv0 = kvb * 64;
      if (kvb + 1 < nkv) {
        // prefetch next kv block into the other buffer (2 loads/thread in flight)
        gload16(Kg0 + (size_t)(kvb + 1) * 64 * NQKV, (char*)Klds[cur ^ 1] + tid * 16);
        gload16(Vg0 + (kvb + 1) * 64,                (char*)Vlds[cur ^ 1] + tid * 16);
        asm volatile("s_waitcnt vmcnt(2)" ::: "memory");
      } else {
        asm volatile("s_waitcnt vmcnt(0)" ::: "memory");
      }
      __builtin_amdgcn_s_barrier();
      __builtin_amdgcn_sched_barrier(0);

      const bool skipw = (kv0 > q_min + 15);
      if (!skipw) {
        const ushort* Kb = Klds[cur];
        const ushort* Vb = Vlds[cur];
        // QK^T
        f32x4 sc[4];
#pragma unroll
        for (int tt = 0; tt < 4; ++tt) {
          int t = tt * 16 + l15;
          int c0 = lg ^ (t & 7);
          int c1 = (lg + 4) ^ (t & 7);
          bf16x8 kf0 = *(const bf16x8*)((const char*)Kb + t * 128 + c0 * 16);
          bf16x8 kf1 = *(const bf16x8*)((const char*)Kb + t * 128 + c1 * 16);
          f32x4 a = {};
          a = mfma16(qf0, kf0, a);
          a = mfma16(qf1, kf1, a);
          sc[tt] = a;
        }
        const bool diag = (kv0 + 63 > q_min);
        if (diag) {
#pragma unroll
          for (int tt = 0; tt < 4; ++tt)
#pragma unroll
            for (int r = 0; r < 4; ++r) {
              int T = kv0 + tt * 16 + l15;
              int Qi = q_min + lg * 4 + r;
              if (T > Qi) sc[tt][r] = -1e30f;
            }
        }
        // row max over 64 t
        float pm[4];
#pragma unroll
        for (int r = 0; r < 4; ++r)
          pm[r] = fmaxf(fmaxf(sc[0][r], sc[1][r]), fmaxf(sc[2][r], sc[3][r]));
#pragma unroll
        for (int msk = 1; msk <= 8; msk <<= 1)
#pragma unroll
          for (int r = 0; r < 4; ++r)
            pm[r] = fmaxf(pm[r], __shfl_xor(pm[r], msk, 64));

        float mnew[4], alpha[4], psum[4];
#pragma unroll
        for (int r = 0; r < 4; ++r) {
          mnew[r] = fmaxf(m_run[r], pm[r]);
          alpha[r] = __expf(m_run[r] - mnew[r]);
          psum[r] = 0.f;
        }
#pragma unroll
        for (int tt = 0; tt < 4; ++tt)
#pragma unroll
          for (int r = 0; r < 4; ++r) {
            float p = __expf(sc[tt][r] - mnew[r]);
            sc[tt][r] = p;
            psum[r] += p;
          }
#pragma unroll
        for (int msk = 1; msk <= 8; msk <<= 1)
#pragma unroll
          for (int r = 0; r < 4; ++r)
            psum[r] += __shfl_xor(psum[r], msk, 64);
#pragma unroll
        for (int r = 0; r < 4; ++r) {
          l_run[r] = l_run[r] * alpha[r] + psum[r];
          m_run[r] = mnew[r];
        }
#pragma unroll
        for (int dt = 0; dt < 4; ++dt)
#pragma unroll
          for (int r = 0; r < 4; ++r) o_acc[dt][r] *= alpha[r];

        // write P to per-wave LDS (swizzled), read back as A-frags
        ushort* Pw = Plds[wave];
#pragma unroll
        for (int tt = 0; tt < 4; ++tt)
#pragma unroll
          for (int r = 0; r < 4; ++r) {
            int q = lg * 4 + r;
            int t = tt * 16 + l15;
            int cs = (t >> 3) ^ (q & 7);
            Pw[q * 64 + cs * 8 + (t & 7)] = f2bf(sc[tt][r]);
          }

        // PV
#pragma unroll
        for (int dt = 0; dt < 4; ++dt) {
          int d = dt * 16 + l15;
#pragma unroll
          for (int kk = 0; kk < 2; ++kk) {
            int cp = (lg + kk * 4) ^ (l15 & 7);
            bf16x8 pf = *(const bf16x8*)((const char*)Pw + l15 * 128 + cp * 16);
            int cv = (lg + kk * 4) ^ (d & 7);
            bf16x8 vf = *(const bf16x8*)((const char*)Vb + d * 128 + cv * 16);
            o_acc[dt] = mfma16(pf, vf, o_acc[dt]);
          }
        }
      }
      __builtin_amdgcn_sched_barrier(0);
      __builtin_amdgcn_s_barrier();
    }

    // epilogue: O[b, q, h*64+d] = o_acc / l_run
    float inv[4];
#pragma unroll
    for (int r = 0; r < 4; ++r) inv[r] = 1.0f / l_run[r];
#pragma unroll
    for (int dt = 0; dt < 4; ++dt)
#pragma unroll
      for (int r = 0; r < 4; ++r) {
        int q = q0 + wave * 16 + lg * 4 + r;
        O[(size_t)(b * SS + q) * DM + h * DD + dt * 16 + l15] = f2bf(o_acc[dt][r] * inv[r]);
      }
  }
}

// ---------- launch ----------
extern "C" void kernel_launch(void* const* d_in, const int* in_sizes, int n_in,
                              void* d_out, int out_size, void* d_ws, size_t ws_size,
                              hipStream_t stream) {
  const float* hs = (const float*)d_in[0];
  const float* Wq = (const float*)d_in[1];
  const float* bq = (const float*)d_in[2];
  const float* Wk = (const float*)d_in[3];
  const float* bk = (const float*)d_in[4];
  const float* Wv = (const float*)d_in[5];
  const float* bv = (const float*)d_in[6];
  const float* Wy = (const float*)d_in[7];
  const float* by = (const float*)d_in[8];
  float* out = (float*)d_out;

  char* ws = (char*)d_ws;
  ushort* Xb   = (ushort*)(ws);                          // 8 MiB  [4096][1024] bf16
  ushort* Wqkv = (ushort*)(ws + (8ull  << 20));          // 6 MiB  [3072][1024] bf16
  ushort* Wyb  = (ushort*)(ws + (14ull << 20));          // 2 MiB  [1024][1024] bf16
  float*  bqkv = (float*) (ws + (16ull << 20));          // 12 KiB
  ushort* QKV  = (ushort*)(ws + (17ull << 20));          // 24 MiB [4096][3072] bf16
  ushort* Vt   = (ushort*)(ws + (41ull << 20));          // 8 MiB  [32][64][2048] bf16
  ushort* Ob   = (ushort*)(ws + (49ull << 20));          // 8 MiB  [4096][1024] bf16

  convert_kernel<<<dim3(8192), dim3(256), 0, stream>>>(hs, Wq, bq, Wk, bk, Wv, bv, Wy,
                                                       Xb, Wqkv, Wyb, bqkv);
  gemm_bt<false><<<dim3(32, 24), dim3(256), 0, stream>>>(Xb, Wqkv, bqkv, QKV,
                                                         MROWS, NQKV, DM, 1024);
  transpose_v<<<dim3(32, 32), dim3(256), 0, stream>>>(QKV, Vt);
  attn_kernel<<<dim3(8, 32), dim3(512), 0, stream>>>(QKV, Vt, Ob);
  gemm_bt<true><<<dim3(32, 8), dim3(256), 0, stream>>>(Ob, Wyb, by, out,
                                                       MROWS, DM, DM, 0);
}

// Round 3
// 115.787 us; speedup vs baseline: 1.5892x; 1.2690x over previous
//
#include <hip/hip_runtime.h>

#define DEV __device__ __forceinline__

typedef __attribute__((ext_vector_type(8))) short bf16x8;
typedef __attribute__((ext_vector_type(4))) float f32x4;
typedef __attribute__((ext_vector_type(16))) float f32x16;

// ---------- helpers ----------
DEV ushort f2bf(float f) {
  union { float f; unsigned u; } x; x.f = f;
  unsigned r = (x.u + 0x7FFFu + ((x.u >> 16) & 1u)) >> 16;
  return (ushort)r;
}

DEV void gload16(const void* g, void* l) {
  __builtin_amdgcn_global_load_lds(
      (const __attribute__((address_space(1))) void*)g,
      (__attribute__((address_space(3))) void*)l, 16, 0, 0);
}

DEV f32x4 mfma16(bf16x8 a, bf16x8 b, f32x4 c) {
  return __builtin_amdgcn_mfma_f32_16x16x32_bf16(a, b, c, 0, 0, 0);
}
DEV f32x16 mfma32(bf16x8 a, bf16x8 b, f32x16 c) {
  return __builtin_amdgcn_mfma_f32_32x32x16_bf16(a, b, c, 0, 0, 0);
}

DEV unsigned cvtpk(float a, float b) {
  unsigned r;
  asm("v_cvt_pk_bf16_f32 %0, %1, %2" : "=v"(r) : "v"(a), "v"(b));
  return r;
}

#if __has_builtin(__builtin_amdgcn_exp2f)
#define EXP2(x) __builtin_amdgcn_exp2f(x)
#else
#define EXP2(x) exp2f(x)
#endif

// ---------- sizes ----------
#define BB 2
#define SS 2048
#define HH 16
#define DD 64
#define DM 1024
#define MROWS (BB * SS)       // 4096
#define NQKV  (3 * DM)        // 3072

// ---------- convert & pack f32 -> bf16 ----------
__global__ void convert_kernel(const float* __restrict__ hs,
                               const float* __restrict__ Wq, const float* __restrict__ bq,
                               const float* __restrict__ Wk, const float* __restrict__ bk,
                               const float* __restrict__ Wv, const float* __restrict__ bv,
                               const float* __restrict__ Wy,
                               ushort* __restrict__ Xb, ushort* __restrict__ Wqkv,
                               ushort* __restrict__ Wyb, float* __restrict__ bqkv) {
  const int HS_V = (MROWS * DM) / 4;     // 1048576
  const int WQ_V = (NQKV * DM) / 4;      // 786432
  const int WY_V = (DM * DM) / 4;        // 262144
  int idx = blockIdx.x * 256 + threadIdx.x;
  if (idx < HS_V) {
    float4 v = ((const float4*)hs)[idx];
    ushort4 o; o.x = f2bf(v.x); o.y = f2bf(v.y); o.z = f2bf(v.z); o.w = f2bf(v.w);
    ((ushort4*)Xb)[idx] = o;
  } else if (idx < HS_V + WQ_V) {
    int e = (idx - HS_V) * 4;
    int n = e >> 10, k = e & 1023;
    const float* W = (n < 1024) ? Wq : (n < 2048) ? Wk : Wv;
    int nn = n & 1023;
    float4 v = *(const float4*)(W + nn * 1024 + k);
    ushort4 o; o.x = f2bf(v.x); o.y = f2bf(v.y); o.z = f2bf(v.z); o.w = f2bf(v.w);
    ((ushort4*)Wqkv)[idx - HS_V] = o;
  } else if (idx < HS_V + WQ_V + WY_V) {
    int e = idx - HS_V - WQ_V;
    float4 v = ((const float4*)Wy)[e];
    ushort4 o; o.x = f2bf(v.x); o.y = f2bf(v.y); o.z = f2bf(v.z); o.w = f2bf(v.w);
    ((ushort4*)Wyb)[e] = o;
  }
  if (idx < NQKV)
    bqkv[idx] = (idx < 1024) ? bq[idx] : (idx < 2048) ? bk[idx - 1024] : bv[idx - 2048];
}

// ---------- GEMM: C[m,n] = (sum_k A[m,k]*Bw[n,k] + bias[n]) * (n<scaleN ? qscale : 1) ----------
template <bool OUT_F32>
__global__ void gemm_bt(const ushort* __restrict__ A, const ushort* __restrict__ Bw,
                        const float* __restrict__ bias, void* __restrict__ Cout,
                        int M, int N, int K, int scaleN, float qscale) {
  __shared__ ushort Al[128 * 32];
  __shared__ ushort Bl[128 * 32];
  const int tid = threadIdx.x;
  const int lane = tid & 63;
  const int wave = tid >> 6;
  const int lg = lane >> 4, l15 = lane & 15;
  const int m0 = blockIdx.x * 128, n0 = blockIdx.y * 128;
  const int wm = (wave >> 1) * 64, wn = (wave & 1) * 64;

  f32x4 acc[4][4] = {};

  for (int k0 = 0; k0 < K; k0 += 32) {
#pragma unroll
    for (int is = 0; is < 2; ++is) {
      int f = tid * 8 + is * 2048;          // bf16 elems
      int row = f >> 5;                     // 0..127
      int c = (f >> 3) & 3;                 // 16B chunk in row
      int cs = c ^ ((row >> 1) & 3);
      gload16(A + (size_t)(m0 + row) * K + k0 + cs * 8,
              (char*)Al + tid * 16 + is * 4096);
      gload16(Bw + (size_t)(n0 + row) * K + k0 + cs * 8,
              (char*)Bl + tid * 16 + is * 4096);
    }
    __syncthreads();

    bf16x8 af[4], bfr[4];
#pragma unroll
    for (int i = 0; i < 4; ++i) {
      int rA = wm + i * 16 + l15;
      int cA = lg ^ ((rA >> 1) & 3);
      af[i] = *(const bf16x8*)((const char*)Al + rA * 64 + cA * 16);
      int rB = wn + i * 16 + l15;
      int cB = lg ^ ((rB >> 1) & 3);
      bfr[i] = *(const bf16x8*)((const char*)Bl + rB * 64 + cB * 16);
    }
#pragma unroll
    for (int i = 0; i < 4; ++i)
#pragma unroll
      for (int j = 0; j < 4; ++j)
        acc[i][j] = mfma16(af[i], bfr[j], acc[i][j]);
    __syncthreads();
  }

#pragma unroll
  for (int i = 0; i < 4; ++i) {
#pragma unroll
    for (int j = 0; j < 4; ++j) {
      int n = n0 + wn + j * 16 + l15;
      float bv = bias[n];
      float qs = (n < scaleN) ? qscale : 1.0f;
#pragma unroll
      for (int r = 0; r < 4; ++r) {
        int m = m0 + wm + i * 16 + lg * 4 + r;
        float v = (acc[i][j][r] + bv) * qs;
        if (OUT_F32)
          ((float*)Cout)[(size_t)m * N + n] = v;
        else
          ((ushort*)Cout)[(size_t)m * N + n] = f2bf(v);
      }
    }
  }
}

// ---------- transpose V section of QKV into Vt [b,h,d,s] ----------
__global__ void transpose_v(const ushort* __restrict__ QKV, ushort* __restrict__ Vt) {
  __shared__ ushort tl[64][72];
  const int tid = threadIdx.x;
  const int bh = blockIdx.y, b = bh >> 4, h = bh & 15;
  const int s0 = blockIdx.x * 64;
  {
    int s = tid >> 2, d0 = (tid & 3) * 16;
    const ushort* src = QKV + (size_t)(b * SS + s0 + s) * NQKV + 2 * DM + h * DD + d0;
    bf16x8 v0 = *(const bf16x8*)(src);
    bf16x8 v1 = *(const bf16x8*)(src + 8);
#pragma unroll
    for (int i = 0; i < 8; ++i) tl[d0 + i][s] = (ushort)v0[i];
#pragma unroll
    for (int i = 0; i < 8; ++i) tl[d0 + 8 + i][s] = (ushort)v1[i];
  }
  __syncthreads();
  {
    int d = tid >> 2, s1 = (tid & 3) * 16;
    ushort* dst = Vt + (size_t)(bh * DD + d) * SS + s0 + s1;
    *(bf16x8*)(dst) = *(const bf16x8*)&tl[d][s1];
    *(bf16x8*)(dst + 8) = *(const bf16x8*)&tl[d][s1 + 8];
  }
}

// ---------- flash attention: 32x32 MFMA, in-register softmax (no max, ref-faithful) ----
// grid (16, 32) = 512 blocks, 256 thr = 4 waves, wave owns 32 q rows (QBLK=128, KVBLK=64).
// Balance: qtile = (y<16) ? 15-x : x  => block n and n+256 (same CU under round-robin)
// have qtiles summing to 15 => combined 34 kv-iters per CU pair.
__global__ __launch_bounds__(256, 2)
void attn_kernel(const ushort* __restrict__ QKV, const ushort* __restrict__ Vt,
                 ushort* __restrict__ Ob) {
  __shared__ ushort Klds[2][64 * 64];   // [t][d] chunk-swizzled ^ (t&7)
  __shared__ ushort Vlds[2][64 * 64];   // [d][t] chunk-swizzled ^ (d&7)

  const int tid = threadIdx.x;
  const int wave = tid >> 6, lane = tid & 63;
  const int l31 = lane & 31, hi = lane >> 5;
  const int bh = blockIdx.y, b = bh >> 4, h = bh & 15;
  const int qtile = (blockIdx.y < 16) ? (15 - (int)blockIdx.x) : (int)blockIdx.x;
  const int q0 = qtile * 128;
  const int nkv = 2 * qtile + 2;
  const int qw = q0 + wave * 32;
  const int q_lane = qw + l31;

  // probe v_permlane32_swap direction (wave-uniform, both HW semantics handled)
  int px = lane, pw = 1000;
  asm volatile("v_permlane32_swap_b32 %0, %1" : "+v"(px), "+v"(pw));
  const bool defA = (__builtin_amdgcn_readfirstlane(px) == 0);

  // staging addresses
  const int sr = tid >> 3;                 // row 0..31 (+32 on 2nd pass)
  const int cs = (tid & 7) ^ (sr & 7);     // swizzled 16B chunk
  const ushort* Kg = QKV + (size_t)(b * SS + sr) * NQKV + DM + h * 64 + cs * 8;
  const ushort* Vg = Vt + (size_t)(bh * 64 + sr) * SS + cs * 8;

#define STAGE(buf, kv0_) do {                                          \
    const ushort* kg_ = Kg + (size_t)(kv0_) * NQKV;                    \
    const ushort* vg_ = Vg + (kv0_);                                   \
    gload16(kg_,             (char*)Klds[buf] + tid * 16);             \
    gload16(kg_ + 32 * NQKV, (char*)Klds[buf] + tid * 16 + 4096);      \
    gload16(vg_,             (char*)Vlds[buf] + tid * 16);             \
    gload16(vg_ + 32 * SS,   (char*)Vlds[buf] + tid * 16 + 4096);      \
  } while (0)

  STAGE(0, 0);

  // Q B-fragments (row q = qw + l31), log2e/8 scale folded in by GEMM epilogue
  const ushort* Qrow = QKV + (size_t)(b * SS + q_lane) * NQKV + h * 64 + hi * 8;
  bf16x8 qf0 = *(const bf16x8*)(Qrow);
  bf16x8 qf1 = *(const bf16x8*)(Qrow + 16);
  bf16x8 qf2 = *(const bf16x8*)(Qrow + 32);
  bf16x8 qf3 = *(const bf16x8*)(Qrow + 48);

  f32x16 acc0 = {}, acc1 = {};
  float psum = 0.f;

  union U4 { unsigned u[4]; bf16x8 v; };

// pack 8 f32 scores (regs R..R+7 of sv) into one PV B-frag (4 dwords) via
// cvt_pk_bf16 + permlane32_swap (direction-probed)
#define PACKH(sv, R, D0, D1, D2, D3) do {                              \
    unsigned X = cvtpk(sv[R + 0], sv[R + 1]);                          \
    unsigned Y = cvtpk(sv[R + 2], sv[R + 3]);                          \
    unsigned W = cvtpk(sv[R + 4], sv[R + 5]);                          \
    unsigned Z = cvtpk(sv[R + 6], sv[R + 7]);                          \
    if (defA) {                                                        \
      asm volatile("v_permlane32_swap_b32 %0, %1" : "+v"(X), "+v"(W)); \
      asm volatile("v_permlane32_swap_b32 %0, %1" : "+v"(Y), "+v"(Z)); \
    } else {                                                           \
      asm volatile("v_permlane32_swap_b32 %0, %1" : "+v"(W), "+v"(X)); \
      asm volatile("v_permlane32_swap_b32 %0, %1" : "+v"(Z), "+v"(Y)); \
    }                                                                  \
    D0 = X; D1 = Y; D2 = W; D3 = Z;                                    \
  } while (0)

  for (int kvb = 0; kvb < nkv; ++kvb) {
    const int cur = kvb & 1;
    const int kv0 = kvb * 64;
    if (kvb + 1 < nkv) {
      STAGE(cur ^ 1, kv0 + 64);
      asm volatile("s_waitcnt vmcnt(4)" ::: "memory");
    } else {
      asm volatile("s_waitcnt vmcnt(0)" ::: "memory");
    }
    __builtin_amdgcn_s_barrier();
    __builtin_amdgcn_sched_barrier(0);

    if (kv0 <= qw + 31) {   // wave has at least one unmasked row in this kv block
      const char* Kb = (const char*)Klds[cur];
      const char* Vb = (const char*)Vlds[cur];

      // QK^T (swapped): s[t][q], t-tiles {0..31},{32..63}
      f32x16 s0 = {}, s1 = {};
#pragma unroll
      for (int ks = 0; ks < 4; ++ks) {
        const int ch = (((ks * 2 + hi) ^ (l31 & 7)) * 16);
        bf16x8 kfa = *(const bf16x8*)(Kb + l31 * 128 + ch);
        bf16x8 kfb = *(const bf16x8*)(Kb + (l31 + 32) * 128 + ch);
        bf16x8 qk = (ks == 0) ? qf0 : (ks == 1) ? qf1 : (ks == 2) ? qf2 : qf3;
        s0 = mfma32(kfa, qk, s0);
        s1 = mfma32(kfb, qk, s1);
      }

      // causal mask (diag blocks only)
      if (kv0 + 63 > qw) {
#pragma unroll
        for (int r = 0; r < 16; ++r) {
          const int tb = (r & 3) + 8 * (r >> 2) + 4 * hi;
          if (kv0 + tb > q_lane) s0[r] = -1e30f;
          if (kv0 + 32 + tb > q_lane) s1[r] = -1e30f;
        }
      }

      // exp2 (scores pre-scaled by log2e/8), in-register psum
#pragma unroll
      for (int r = 0; r < 16; ++r) {
        float p0 = EXP2(s0[r]);
        float p1 = EXP2(s1[r]);
        s0[r] = p0; s1[r] = p1;
        psum += p0 + p1;
      }

      // pack P -> 4 PV B-frags, fully in-register
      U4 f0, f1, f2, f3;
      PACKH(s0, 0, f0.u[0], f0.u[1], f0.u[2], f0.u[3]);
      PACKH(s0, 8, f1.u[0], f1.u[1], f1.u[2], f1.u[3]);
      PACKH(s1, 0, f2.u[0], f2.u[1], f2.u[2], f2.u[3]);
      PACKH(s1, 8, f3.u[0], f3.u[1], f3.u[2], f3.u[3]);

      // PV: O^T[d][q] += V^T[d][t] * P^T[t][q]
#pragma unroll
      for (int ts = 0; ts < 4; ++ts) {
        const int ch = (((ts * 2 + hi) ^ (l31 & 7)) * 16);
        bf16x8 vfa = *(const bf16x8*)(Vb + l31 * 128 + ch);
        bf16x8 vfb = *(const bf16x8*)(Vb + (l31 + 32) * 128 + ch);
        bf16x8 pf = (ts == 0) ? f0.v : (ts == 1) ? f1.v : (ts == 2) ? f2.v : f3.v;
        acc0 = mfma32(vfa, pf, acc0);
        acc1 = mfma32(vfb, pf, acc1);
      }
    }
    __builtin_amdgcn_sched_barrier(0);
    __builtin_amdgcn_s_barrier();
  }

  // epilogue: combine lane/lane^32 partial sums, normalize, store O (bf16)
  float tot = psum + __shfl_xor(psum, 32, 64);
  float inv = 1.0f / tot;
  ushort* orow = Ob + (size_t)(b * SS + q_lane) * DM + h * 64;
#pragma unroll
  for (int g = 0; g < 4; ++g) {
    uint2 st;
    st.x = cvtpk(acc0[4 * g + 0] * inv, acc0[4 * g + 1] * inv);
    st.y = cvtpk(acc0[4 * g + 2] * inv, acc0[4 * g + 3] * inv);
    *(uint2*)(orow + 8 * g + 4 * hi) = st;
    uint2 st2;
    st2.x = cvtpk(acc1[4 * g + 0] * inv, acc1[4 * g + 1] * inv);
    st2.y = cvtpk(acc1[4 * g + 2] * inv, acc1[4 * g + 3] * inv);
    *(uint2*)(orow + 32 + 8 * g + 4 * hi) = st2;
  }
#undef STAGE
#undef PACKH
}

// ---------- launch ----------
extern "C" void kernel_launch(void* const* d_in, const int* in_sizes, int n_in,
                              void* d_out, int out_size, void* d_ws, size_t ws_size,
                              hipStream_t stream) {
  const float* hs = (const float*)d_in[0];
  const float* Wq = (const float*)d_in[1];
  const float* bq = (const float*)d_in[2];
  const float* Wk = (const float*)d_in[3];
  const float* bk = (const float*)d_in[4];
  const float* Wv = (const float*)d_in[5];
  const float* bv = (const float*)d_in[6];
  const float* Wy = (const float*)d_in[7];
  const float* by = (const float*)d_in[8];
  float* out = (float*)d_out;

  char* ws = (char*)d_ws;
  ushort* Xb   = (ushort*)(ws);                          // 8 MiB  [4096][1024] bf16
  ushort* Wqkv = (ushort*)(ws + (8ull  << 20));          // 6 MiB  [3072][1024] bf16
  ushort* Wyb  = (ushort*)(ws + (14ull << 20));          // 2 MiB  [1024][1024] bf16
  float*  bqkv = (float*) (ws + (16ull << 20));          // 12 KiB
  ushort* QKV  = (ushort*)(ws + (17ull << 20));          // 24 MiB [4096][3072] bf16
  ushort* Vt   = (ushort*)(ws + (41ull << 20));          // 8 MiB  [32][64][2048] bf16
  ushort* Ob   = (ushort*)(ws + (49ull << 20));          // 8 MiB  [4096][1024] bf16

  const float QSC = 0.125f * 1.44269504088896f;  // fold 1/sqrt(D) * log2(e) into Q

  convert_kernel<<<dim3(8192), dim3(256), 0, stream>>>(hs, Wq, bq, Wk, bk, Wv, bv, Wy,
                                                       Xb, Wqkv, Wyb, bqkv);
  gemm_bt<false><<<dim3(32, 24), dim3(256), 0, stream>>>(Xb, Wqkv, bqkv, QKV,
                                                         MROWS, NQKV, DM, 1024, QSC);
  transpose_v<<<dim3(32, 32), dim3(256), 0, stream>>>(QKV, Vt);
  attn_kernel<<<dim3(16, 32), dim3(256), 0, stream>>>(QKV, Vt, Ob);
  gemm_bt<true><<<dim3(32, 8), dim3(256), 0, stream>>>(Ob, Wyb, by, out,
                                                       MROWS, DM, DM, 0, 1.0f);
}

// Round 4
// 93.198 us; speedup vs baseline: 1.9743x; 1.2424x over previous
//
#include <hip/hip_runtime.h>

#define DEV __device__ __forceinline__

typedef __attribute__((ext_vector_type(8))) short bf16x8;
typedef __attribute__((ext_vector_type(4))) float f32x4;
typedef __attribute__((ext_vector_type(16))) float f32x16;

// ---------- helpers ----------
DEV ushort f2bf(float f) {
  union { float f; unsigned u; } x; x.f = f;
  unsigned r = (x.u + 0x7FFFu + ((x.u >> 16) & 1u)) >> 16;
  return (ushort)r;
}

DEV void gload16(const void* g, void* l) {
  __builtin_amdgcn_global_load_lds(
      (const __attribute__((address_space(1))) void*)g,
      (__attribute__((address_space(3))) void*)l, 16, 0, 0);
}

DEV f32x4 mfma16(bf16x8 a, bf16x8 b, f32x4 c) {
  return __builtin_amdgcn_mfma_f32_16x16x32_bf16(a, b, c, 0, 0, 0);
}
DEV f32x16 mfma32(bf16x8 a, bf16x8 b, f32x16 c) {
  return __builtin_amdgcn_mfma_f32_32x32x16_bf16(a, b, c, 0, 0, 0);
}

DEV unsigned cvtpk(float a, float b) {
  unsigned r;
  asm("v_cvt_pk_bf16_f32 %0, %1, %2" : "=v"(r) : "v"(a), "v"(b));
  return r;
}

#if __has_builtin(__builtin_amdgcn_exp2f)
#define EXP2(x) __builtin_amdgcn_exp2f(x)
#else
#define EXP2(x) exp2f(x)
#endif

// ---------- sizes ----------
#define BB 2
#define SS 2048
#define HH 16
#define DD 64
#define DM 1024
#define MROWS (BB * SS)       // 4096
#define NQKV  (3 * DM)        // 3072

// ---------- convert & pack f32 -> bf16 ----------
__global__ void convert_kernel(const float* __restrict__ hs,
                               const float* __restrict__ Wq, const float* __restrict__ bq,
                               const float* __restrict__ Wk, const float* __restrict__ bk,
                               const float* __restrict__ Wv, const float* __restrict__ bv,
                               const float* __restrict__ Wy,
                               ushort* __restrict__ Xb, ushort* __restrict__ Wqkv,
                               ushort* __restrict__ Wyb, float* __restrict__ bqkv) {
  const int HS_V = (MROWS * DM) / 4;     // 1048576
  const int WQ_V = (NQKV * DM) / 4;      // 786432
  const int WY_V = (DM * DM) / 4;        // 262144
  int idx = blockIdx.x * 256 + threadIdx.x;
  if (idx < HS_V) {
    float4 v = ((const float4*)hs)[idx];
    ushort4 o; o.x = f2bf(v.x); o.y = f2bf(v.y); o.z = f2bf(v.z); o.w = f2bf(v.w);
    ((ushort4*)Xb)[idx] = o;
  } else if (idx < HS_V + WQ_V) {
    int e = (idx - HS_V) * 4;
    int n = e >> 10, k = e & 1023;
    const float* W = (n < 1024) ? Wq : (n < 2048) ? Wk : Wv;
    int nn = n & 1023;
    float4 v = *(const float4*)(W + nn * 1024 + k);
    ushort4 o; o.x = f2bf(v.x); o.y = f2bf(v.y); o.z = f2bf(v.z); o.w = f2bf(v.w);
    ((ushort4*)Wqkv)[idx - HS_V] = o;
  } else if (idx < HS_V + WQ_V + WY_V) {
    int e = idx - HS_V - WQ_V;
    float4 v = ((const float4*)Wy)[e];
    ushort4 o; o.x = f2bf(v.x); o.y = f2bf(v.y); o.z = f2bf(v.z); o.w = f2bf(v.w);
    ((ushort4*)Wyb)[e] = o;
  }
  if (idx < NQKV)
    bqkv[idx] = (idx < 1024) ? bq[idx] : (idx < 2048) ? bk[idx - 1024] : bv[idx - 2048];
}

// ---------- GEMM (m97 recipe): BK=64, BM=64*MI, BN=128 ----------
// C[m,n] = (sum_k A[m,k]*Bw[n,k] + bias[n]) * (n<scaleN ? qscale : 1)
template <int MI, bool OUT_F32>
__global__ void gemm_bt(const ushort* __restrict__ A, const ushort* __restrict__ Bw,
                        const float* __restrict__ bias, void* __restrict__ Cout,
                        int M, int N, int K, int scaleN, float qscale) {
  constexpr int BM = 64 * MI;
  constexpr int NI = BM / 32;           // 16-row acc frags per wave (m dir)
  __shared__ ushort Al[BM * 64];
  __shared__ ushort Bl[128 * 64];
  const int tid = threadIdx.x;
  const int lane = tid & 63;
  const int wave = tid >> 6;
  const int lg = lane >> 4, l15 = lane & 15;
  const int m0 = blockIdx.x * BM, n0 = blockIdx.y * 128;
  const int wm = (wave >> 1) * (BM / 2), wn = (wave & 1) * 64;

  f32x4 acc[NI][4] = {};

  for (int k0 = 0; k0 < K; k0 += 64) {
    // stage A (BM x 64) and B (128 x 64), chunk-swizzled via global source
#pragma unroll
    for (int s = 0; s < BM * 8 / 256; ++s) {
      int f = tid + s * 256;
      int row = f >> 3, c = f & 7, cs = c ^ (row & 7);
      gload16(A + (size_t)(m0 + row) * K + k0 + cs * 8, (char*)Al + f * 16);
    }
#pragma unroll
    for (int s = 0; s < 4; ++s) {
      int f = tid + s * 256;
      int row = f >> 3, c = f & 7, cs = c ^ (row & 7);
      gload16(Bw + (size_t)(n0 + row) * K + k0 + cs * 8, (char*)Bl + f * 16);
    }
    __syncthreads();

#pragma unroll
    for (int kk = 0; kk < 2; ++kk) {
      bf16x8 af[NI], bfr[4];
#pragma unroll
      for (int i = 0; i < NI; ++i) {
        int rA = wm + i * 16 + l15;
        int cA = (kk * 4 + lg) ^ (rA & 7);
        af[i] = *(const bf16x8*)((const char*)Al + rA * 128 + cA * 16);
      }
#pragma unroll
      for (int j = 0; j < 4; ++j) {
        int rB = wn + j * 16 + l15;
        int cB = (kk * 4 + lg) ^ (rB & 7);
        bfr[j] = *(const bf16x8*)((const char*)Bl + rB * 128 + cB * 16);
      }
#pragma unroll
      for (int i = 0; i < NI; ++i)
#pragma unroll
        for (int j = 0; j < 4; ++j)
          acc[i][j] = mfma16(af[i], bfr[j], acc[i][j]);
    }
    __syncthreads();
  }

#pragma unroll
  for (int i = 0; i < NI; ++i) {
#pragma unroll
    for (int j = 0; j < 4; ++j) {
      int n = n0 + wn + j * 16 + l15;
      float bv = bias[n];
      float qs = (n < scaleN) ? qscale : 1.0f;
#pragma unroll
      for (int r = 0; r < 4; ++r) {
        int m = m0 + wm + i * 16 + lg * 4 + r;
        float v = (acc[i][j][r] + bv) * qs;
        if (OUT_F32)
          ((float*)Cout)[(size_t)m * N + n] = v;
        else
          ((ushort*)Cout)[(size_t)m * N + n] = f2bf(v);
      }
    }
  }
}

// ---------- transpose V section of QKV into Vt [b,h,d,s] ----------
__global__ void transpose_v(const ushort* __restrict__ QKV, ushort* __restrict__ Vt) {
  __shared__ ushort tl[64][72];
  const int tid = threadIdx.x;
  const int bh = blockIdx.y, b = bh >> 4, h = bh & 15;
  const int s0 = blockIdx.x * 64;
  {
    int s = tid >> 2, d0 = (tid & 3) * 16;
    const ushort* src = QKV + (size_t)(b * SS + s0 + s) * NQKV + 2 * DM + h * DD + d0;
    bf16x8 v0 = *(const bf16x8*)(src);
    bf16x8 v1 = *(const bf16x8*)(src + 8);
#pragma unroll
    for (int i = 0; i < 8; ++i) tl[d0 + i][s] = (ushort)v0[i];
#pragma unroll
    for (int i = 0; i < 8; ++i) tl[d0 + 8 + i][s] = (ushort)v1[i];
  }
  __syncthreads();
  {
    int d = tid >> 2, s1 = (tid & 3) * 16;
    ushort* dst = Vt + (size_t)(bh * DD + d) * SS + s0 + s1;
    *(bf16x8*)(dst) = *(const bf16x8*)&tl[d][s1];
    *(bf16x8*)(dst + 8) = *(const bf16x8*)&tl[d][s1 + 8];
  }
}

// ---------- flash attention: split-K groups + sequential qtile pairing ----------
// grid 512 x 256thr = 4 waves. QBLK=64 (waves 0/1 = q halves), groups {w0,w1},{w2,w3}
// process even/odd KV blocks (KVBLK=64) with private double-buffers; partial
// (o_acc, psum) merged via LDS (valid: reference softmax has no max-subtraction,
// so partials are pure sums). Qtile pair {x, 31-x} => every block ~17 iters flat.
__global__ __launch_bounds__(256, 2)
void attn_kernel(const ushort* __restrict__ QKV, const ushort* __restrict__ Vt,
                 ushort* __restrict__ Ob) {
  __shared__ __align__(16) char SMEM[65536];
  // K(g,d): SMEM + (g*2+d)*8192      (32 KB)
  // V(g,d): SMEM + 32768 + (g*2+d)*8192 (32 KB)
  // merge: acc f32x4 [8][128] at SMEM+0 (16 KB, overlays group0 K bufs)
  //        psum f32 [128] at SMEM+32768 (overlays group0 V buf)

  const int tid = threadIdx.x;
  const int wave = tid >> 6, lane = tid & 63;
  const int l31 = lane & 31, hi = lane >> 5;
  const int grp = wave >> 1, wq = wave & 1;

  // XCD-locality swizzle: bh&7 == n&7 => each XCD sees 4 bh (2MB KV, fits L2)
  const int n = blockIdx.x;
  const int bh = (n & 7) | ((n >> 7) << 3);
  const int pairi = (n >> 3) & 15;
  const int b = bh >> 4, h = bh & 15;

  // probe v_permlane32_swap direction (wave-uniform)
  int px = lane, pw = 1000;
  asm volatile("v_permlane32_swap_b32 %0, %1" : "+v"(px), "+v"(pw));
  const bool defA = (__builtin_amdgcn_readfirstlane(px) == 0);

  // staging addresses: group threads gtid 0..127 cover 64 rows x 8 chunks in 4 steps
  const int gtid = tid & 127;
  const int srow = gtid >> 3;                         // base row (step adds 16)
  const int scs = (gtid & 7) ^ (srow & 7);            // swizzled chunk (row&7 invariant mod 16)
  const ushort* Kg = QKV + (size_t)(b * SS + srow) * NQKV + DM + h * 64 + scs * 8;
  const ushort* Vg = Vt + (size_t)(bh * 64 + srow) * SS + scs * 8;

#define STAGE(d_, kv0_) do {                                            \
    const ushort* kg_ = Kg + (size_t)(kv0_) * NQKV;                     \
    const ushort* vg_ = Vg + (kv0_);                                    \
    char* kl_ = SMEM + (grp * 2 + (d_)) * 8192 + gtid * 16;             \
    char* vl_ = SMEM + 32768 + (grp * 2 + (d_)) * 8192 + gtid * 16;     \
    _Pragma("unroll")                                                   \
    for (int s_ = 0; s_ < 4; ++s_) {                                    \
      gload16(kg_ + (size_t)s_ * 16 * NQKV, kl_ + s_ * 2048);           \
      gload16(vg_ + (size_t)s_ * 16 * SS,   vl_ + s_ * 2048);           \
    }                                                                   \
  } while (0)

  union U4 { unsigned u[4]; bf16x8 v; };

#define PACKH(sv, R, D0, D1, D2, D3) do {                              \
    unsigned X = cvtpk(sv[R + 0], sv[R + 1]);                          \
    unsigned Y = cvtpk(sv[R + 2], sv[R + 3]);                          \
    unsigned W = cvtpk(sv[R + 4], sv[R + 5]);                          \
    unsigned Z = cvtpk(sv[R + 6], sv[R + 7]);                          \
    if (defA) {                                                        \
      asm volatile("v_permlane32_swap_b32 %0, %1" : "+v"(X), "+v"(W)); \
      asm volatile("v_permlane32_swap_b32 %0, %1" : "+v"(Y), "+v"(Z)); \
    } else {                                                           \
      asm volatile("v_permlane32_swap_b32 %0, %1" : "+v"(W), "+v"(X)); \
      asm volatile("v_permlane32_swap_b32 %0, %1" : "+v"(Z), "+v"(Y)); \
    }                                                                  \
    D0 = X; D1 = Y; D2 = W; D3 = Z;                                    \
  } while (0)

#pragma unroll 1
  for (int ph = 0; ph < 2; ++ph) {
    // protects merge area of previous phase from this phase's staging
    __builtin_amdgcn_s_barrier();

    const int qt = ph ? (31 - pairi) : pairi;
    const int q0 = qt * 64;
    const int nkv = qt + 1;
    const int niter = (nkv + 1) >> 1;
    const int qw = q0 + wq * 32;
    const int q_lane = qw + l31;

    // Q B-frags (scale log2e/8 folded in by QKV GEMM epilogue)
    const ushort* Qrow = QKV + (size_t)(b * SS + q_lane) * NQKV + h * 64 + hi * 8;
    bf16x8 qf0 = *(const bf16x8*)(Qrow);
    bf16x8 qf1 = *(const bf16x8*)(Qrow + 16);
    bf16x8 qf2 = *(const bf16x8*)(Qrow + 32);
    bf16x8 qf3 = *(const bf16x8*)(Qrow + 48);

    f32x16 acc0 = {}, acc1 = {};
    float ps0 = 0.f, ps1 = 0.f, ps2 = 0.f, ps3 = 0.f;

    if (grp < nkv) STAGE(0, grp * 64);
    int buf = 0;

#pragma unroll 1
    for (int it = 0; it < niter; ++it) {
      const int j = 2 * it + grp;
      if (j + 2 < nkv) {
        STAGE(buf ^ 1, (j + 2) * 64);
        asm volatile("s_waitcnt vmcnt(8)" ::: "memory");
      } else {
        asm volatile("s_waitcnt vmcnt(0)" ::: "memory");
      }
      __builtin_amdgcn_s_barrier();
      __builtin_amdgcn_sched_barrier(0);

      if (j < nkv) {
        const int kv0 = j * 64;
        const char* Kb = SMEM + (grp * 2 + buf) * 8192;
        const char* Vb = SMEM + 32768 + (grp * 2 + buf) * 8192;

        // QK^T (swapped): s[t][q]
        f32x16 s0 = {}, s1 = {};
        __builtin_amdgcn_s_setprio(1);
#pragma unroll
        for (int ks = 0; ks < 4; ++ks) {
          const int ch = (((ks * 2 + hi) ^ (l31 & 7)) * 16);
          bf16x8 kfa = *(const bf16x8*)(Kb + l31 * 128 + ch);
          bf16x8 kfb = *(const bf16x8*)(Kb + (l31 + 32) * 128 + ch);
          bf16x8 qk = (ks == 0) ? qf0 : (ks == 1) ? qf1 : (ks == 2) ? qf2 : qf3;
          s0 = mfma32(kfa, qk, s0);
          s1 = mfma32(kfb, qk, s1);
        }
        __builtin_amdgcn_s_setprio(0);

        if (j == qt) {  // diagonal block: causal mask
#pragma unroll
          for (int r = 0; r < 16; ++r) {
            const int tb = (r & 3) + 8 * (r >> 2) + 4 * hi;
            if (kv0 + tb > q_lane) s0[r] = -1e30f;
            if (kv0 + 32 + tb > q_lane) s1[r] = -1e30f;
          }
        }

        // exp2 + 4-way psum accumulators (shorter dep chain)
#pragma unroll
        for (int r = 0; r < 16; r += 4) {
          float a0 = EXP2(s0[r]), a1 = EXP2(s0[r + 1]), a2 = EXP2(s0[r + 2]), a3 = EXP2(s0[r + 3]);
          s0[r] = a0; s0[r + 1] = a1; s0[r + 2] = a2; s0[r + 3] = a3;
          ps0 += a0; ps1 += a1; ps2 += a2; ps3 += a3;
          float b0 = EXP2(s1[r]), b1 = EXP2(s1[r + 1]), b2 = EXP2(s1[r + 2]), b3 = EXP2(s1[r + 3]);
          s1[r] = b0; s1[r + 1] = b1; s1[r + 2] = b2; s1[r + 3] = b3;
          ps0 += b0; ps1 += b1; ps2 += b2; ps3 += b3;
        }

        // pack P -> PV B-frags in registers
        U4 f0, f1, f2, f3;
        PACKH(s0, 0, f0.u[0], f0.u[1], f0.u[2], f0.u[3]);
        PACKH(s0, 8, f1.u[0], f1.u[1], f1.u[2], f1.u[3]);
        PACKH(s1, 0, f2.u[0], f2.u[1], f2.u[2], f2.u[3]);
        PACKH(s1, 8, f3.u[0], f3.u[1], f3.u[2], f3.u[3]);

        // PV: O^T[d][q] += V^T[d][t] * P^T[t][q]
        __builtin_amdgcn_s_setprio(1);
#pragma unroll
        for (int ts = 0; ts < 4; ++ts) {
          const int ch = (((ts * 2 + hi) ^ (l31 & 7)) * 16);
          bf16x8 vfa = *(const bf16x8*)(Vb + l31 * 128 + ch);
          bf16x8 vfb = *(const bf16x8*)(Vb + (l31 + 32) * 128 + ch);
          bf16x8 pf = (ts == 0) ? f0.v : (ts == 1) ? f1.v : (ts == 2) ? f2.v : f3.v;
          acc0 = mfma32(vfa, pf, acc0);
          acc1 = mfma32(vfb, pf, acc1);
        }
        __builtin_amdgcn_s_setprio(0);
      }
      __builtin_amdgcn_sched_barrier(0);
      __builtin_amdgcn_s_barrier();
      buf ^= 1;
    }

    // ---- merge group partials (pure sums; no rescale needed) ----
    float psum = ps0 + ps1 + ps2 + ps3;
    f32x4* MA = (f32x4*)SMEM;            // [8][128], lane-major (conflict-free)
    float* MP = (float*)(SMEM + 32768);  // [128]
    const int slot = wq * 64 + lane;
    if (grp == 1) {
#pragma unroll
      for (int c = 0; c < 4; ++c) {
        f32x4 t0 = {acc0[4 * c], acc0[4 * c + 1], acc0[4 * c + 2], acc0[4 * c + 3]};
        MA[c * 128 + slot] = t0;
        f32x4 t1 = {acc1[4 * c], acc1[4 * c + 1], acc1[4 * c + 2], acc1[4 * c + 3]};
        MA[(c + 4) * 128 + slot] = t1;
      }
      MP[slot] = psum;
    }
    __builtin_amdgcn_s_barrier();
    if (grp == 0) {
#pragma unroll
      for (int c = 0; c < 4; ++c) {
        f32x4 t0 = MA[c * 128 + slot];
        f32x4 t1 = MA[(c + 4) * 128 + slot];
        acc0[4 * c] += t0[0]; acc0[4 * c + 1] += t0[1];
        acc0[4 * c + 2] += t0[2]; acc0[4 * c + 3] += t0[3];
        acc1[4 * c] += t1[0]; acc1[4 * c + 1] += t1[1];
        acc1[4 * c + 2] += t1[2]; acc1[4 * c + 3] += t1[3];
      }
      psum += MP[slot];
      float tot = psum + __shfl_xor(psum, 32, 64);
      float inv = 1.0f / tot;
      ushort* orow = Ob + (size_t)(b * SS + q_lane) * DM + h * 64;
#pragma unroll
      for (int g = 0; g < 4; ++g) {
        uint2 st;
        st.x = cvtpk(acc0[4 * g + 0] * inv, acc0[4 * g + 1] * inv);
        st.y = cvtpk(acc0[4 * g + 2] * inv, acc0[4 * g + 3] * inv);
        *(uint2*)(orow + 8 * g + 4 * hi) = st;
        uint2 st2;
        st2.x = cvtpk(acc1[4 * g + 0] * inv, acc1[4 * g + 1] * inv);
        st2.y = cvtpk(acc1[4 * g + 2] * inv, acc1[4 * g + 3] * inv);
        *(uint2*)(orow + 32 + 8 * g + 4 * hi) = st2;
      }
    }
  }
#undef STAGE
#undef PACKH
}

// ---------- launch ----------
extern "C" void kernel_launch(void* const* d_in, const int* in_sizes, int n_in,
                              void* d_out, int out_size, void* d_ws, size_t ws_size,
                              hipStream_t stream) {
  const float* hs = (const float*)d_in[0];
  const float* Wq = (const float*)d_in[1];
  const float* bq = (const float*)d_in[2];
  const float* Wk = (const float*)d_in[3];
  const float* bk = (const float*)d_in[4];
  const float* Wv = (const float*)d_in[5];
  const float* bv = (const float*)d_in[6];
  const float* Wy = (const float*)d_in[7];
  const float* by = (const float*)d_in[8];
  float* out = (float*)d_out;

  char* ws = (char*)d_ws;
  ushort* Xb   = (ushort*)(ws);                          // 8 MiB
  ushort* Wqkv = (ushort*)(ws + (8ull  << 20));          // 6 MiB
  ushort* Wyb  = (ushort*)(ws + (14ull << 20));          // 2 MiB
  float*  bqkv = (float*) (ws + (16ull << 20));          // 12 KiB
  ushort* QKV  = (ushort*)(ws + (17ull << 20));          // 24 MiB
  ushort* Vt   = (ushort*)(ws + (41ull << 20));          // 8 MiB
  ushort* Ob   = (ushort*)(ws + (49ull << 20));          // 8 MiB

  const float QSC = 0.125f * 1.44269504088896f;  // 1/sqrt(D) * log2(e)

  convert_kernel<<<dim3(8192), dim3(256), 0, stream>>>(hs, Wq, bq, Wk, bk, Wv, bv, Wy,
                                                       Xb, Wqkv, Wyb, bqkv);
  gemm_bt<2, false><<<dim3(32, 24), dim3(256), 0, stream>>>(Xb, Wqkv, bqkv, QKV,
                                                            MROWS, NQKV, DM, 1024, QSC);
  transpose_v<<<dim3(32, 32), dim3(256), 0, stream>>>(QKV, Vt);
  attn_kernel<<<dim3(512), dim3(256), 0, stream>>>(QKV, Vt, Ob);
  gemm_bt<1, true><<<dim3(64, 8), dim3(256), 0, stream>>>(Ob, Wyb, by, out,
                                                          MROWS, DM, DM, 0, 1.0f);
}